// Round 13
// baseline (657.519 us; speedup 1.0000x reference)
//
#include <hip/hip_runtime.h>
#include <hip/hip_bf16.h>

// E71 Delta cell: T=2048, B=16, D=1024, N=128
// proj layout in ws: [t][b][512] f32, cols 0..127=k_hat (after norm pass),
// 128..255=v, 256..383=q, 384..511=bx+bb (bb folded in norm pass)

#define T_STEPS 2048
#define NB 16
#define ND 128
#define KD 1024
#define PSTRIDE 512

typedef __attribute__((ext_vector_type(4))) float f32x4;
typedef __attribute__((ext_vector_type(2))) float f32x2;
typedef __attribute__((ext_vector_type(8))) short short8v;

__device__ __forceinline__ unsigned short f2bf(float f) {
  union { float f; unsigned int u; } c; c.f = f;
  unsigned int u = c.u;
  unsigned int r = u + 0x7fffu + ((u >> 16) & 1u);   // round-to-nearest-even
  return (unsigned short)(r >> 16);
}

// ---------------------------------------------------------------------------
// Projection GEMM (unchanged, ~56us): bf16 MFMA, 128x128 tile, BK=64,
// XOR-swizzled LDS.
// ---------------------------------------------------------------------------
__global__ __launch_bounds__(256) void proj_gemm(
    const float* __restrict__ X,
    const float* __restrict__ Wk, const float* __restrict__ Wv,
    const float* __restrict__ Wq, const float* __restrict__ Wb,
    float* __restrict__ C)
{
  __shared__ unsigned short As[128 * 64];
  __shared__ unsigned short Bs[128 * 64];
  const int tid = threadIdx.x;
  const int bm = blockIdx.x;
  const int bn = blockIdx.y;
  const float* W = (bn == 0) ? Wk : ((bn == 1) ? Wv : ((bn == 2) ? Wq : Wb));
  const int lane = tid & 63;
  const int wave = tid >> 6;
  const int wr = wave >> 1, wc = wave & 1;

  f32x4 acc[4][4];
#pragma unroll
  for (int i = 0; i < 4; i++)
#pragma unroll
    for (int j = 0; j < 4; j++) acc[i][j] = (f32x4){0.f, 0.f, 0.f, 0.f};

  for (int k0 = 0; k0 < KD; k0 += 64) {
    __syncthreads();
#pragma unroll
    for (int c = 0; c < 4; c++) {
      const int g = tid + c * 256;
      const int row = g >> 3;
      const int ch = g & 7;
      const int pos = ((ch ^ (row & 7)) * 8);
      {
        const float* ga = X + (size_t)(bm * 128 + row) * KD + k0 + ch * 8;
        float4 f0 = *(const float4*)(ga);
        float4 f1 = *(const float4*)(ga + 4);
        union { unsigned short u[8]; short8v v; } pk2;
        pk2.u[0] = f2bf(f0.x); pk2.u[1] = f2bf(f0.y);
        pk2.u[2] = f2bf(f0.z); pk2.u[3] = f2bf(f0.w);
        pk2.u[4] = f2bf(f1.x); pk2.u[5] = f2bf(f1.y);
        pk2.u[6] = f2bf(f1.z); pk2.u[7] = f2bf(f1.w);
        *reinterpret_cast<short8v*>(&As[row * 64 + pos]) = pk2.v;
      }
      {
        const float* gb = W + (size_t)row * KD + k0 + ch * 8;
        float4 f0 = *(const float4*)(gb);
        float4 f1 = *(const float4*)(gb + 4);
        union { unsigned short u[8]; short8v v; } pk2;
        pk2.u[0] = f2bf(f0.x); pk2.u[1] = f2bf(f0.y);
        pk2.u[2] = f2bf(f0.z); pk2.u[3] = f2bf(f0.w);
        pk2.u[4] = f2bf(f1.x); pk2.u[5] = f2bf(f1.y);
        pk2.u[6] = f2bf(f1.z); pk2.u[7] = f2bf(f1.w);
        *reinterpret_cast<short8v*>(&Bs[row * 64 + pos]) = pk2.v;
      }
    }
    __syncthreads();
#pragma unroll
    for (int kk = 0; kk < 2; kk++) {
      const int ch = kk * 4 + (lane >> 4);
      short8v a[4], b[4];
#pragma unroll
      for (int i = 0; i < 4; i++) {
        const int ar = wr * 64 + i * 16 + (lane & 15);
        a[i] = *reinterpret_cast<const short8v*>(&As[ar * 64 + ((ch ^ (ar & 7)) * 8)]);
        const int br = wc * 64 + i * 16 + (lane & 15);
        b[i] = *reinterpret_cast<const short8v*>(&Bs[br * 64 + ((ch ^ (br & 7)) * 8)]);
      }
#pragma unroll
      for (int i = 0; i < 4; i++)
#pragma unroll
        for (int j = 0; j < 4; j++)
          acc[i][j] = __builtin_amdgcn_mfma_f32_16x16x32_bf16(a[i], b[j], acc[i][j], 0, 0, 0);
    }
  }
#pragma unroll
  for (int i = 0; i < 4; i++)
#pragma unroll
    for (int j = 0; j < 4; j++)
#pragma unroll
      for (int r = 0; r < 4; r++) {
        const int row = bm * 128 + wr * 64 + i * 16 + (lane >> 4) * 4 + r;
        const int col = bn * 128 + wc * 64 + j * 16 + (lane & 15);
        C[(size_t)row * PSTRIDE + col] = acc[i][j][r];
      }
}

// ---------------------------------------------------------------------------
// k-normalization pre-pass: proj[row][0:128] <- k/(||k||+eps); also folds
// b_beta into the bx column: proj[row][384:512] += bb.
// ---------------------------------------------------------------------------
__global__ __launch_bounds__(256) void norm_k(float* __restrict__ proj,
                                              const float* __restrict__ b_beta) {
  const int lane = threadIdx.x & 63;
  const int wid = (blockIdx.x * 256 + threadIdx.x) >> 6;
  float* rowp = proj + (size_t)wid * PSTRIDE;
  float2 kv = *reinterpret_cast<float2*>(rowp + lane * 2);
  float ss = kv.x * kv.x + kv.y * kv.y;
  ss += __shfl_xor(ss, 1);
  ss += __shfl_xor(ss, 2);
  ss += __shfl_xor(ss, 4);
  ss += __shfl_xor(ss, 8);
  ss += __shfl_xor(ss, 16);
  ss += __shfl_xor(ss, 32);
  const float rn = 1.0f / (sqrtf(ss) + 1e-6f);
  kv.x *= rn; kv.y *= rn;
  *reinterpret_cast<float2*>(rowp + lane * 2) = kv;
  // fold bb into bx column
  float2 bx = *reinterpret_cast<float2*>(rowp + 384 + lane * 2);
  const float2 bb = *reinterpret_cast<const float2*>(b_beta + lane * 2);
  bx.x += bb.x; bx.y += bb.y;
  *reinterpret_cast<float2*>(rowp + 384 + lane * 2) = bx;
}

// ---------------------------------------------------------------------------
// Sequential scan, R13: DUAL-CHAIN per wave.
// 256 single-wave blocks (1/CU, all CUs). Wave: batchA = bid&7, batchB =
// batchA+8 (both on XCD bid&7), rows grp*4..grp*4+3 (grp = bid>>3).
// Lane layout per chain (R7, proven): 16 lanes/row (cc = lane&15 -> 8 cols),
// rloc = lane>>4. The two chains are independent register dataflow in one
// scheduling region -> compiler interleaves; chain B's issue fills chain A's
// ~300cy dependency-chain stall (intra-wave ILP; TLP impossible at 512 waves).
// Depth-4 saddr-form asm ring per chain (offsets self-advance, no 64-bit
// addr math); uniform counted vmcnt(36) (safe for prologue and steady).
// amdgpu_waves_per_eu(1,1): 512-VGPR budget, no occupancy-driven spill.
// Reduce: all-DPP row_ror 8/4/2/1. fin+store deferred one slot (off-chain).
// ---------------------------------------------------------------------------
__device__ __forceinline__ float sum16r(float v) {
  v += __int_as_float(__builtin_amdgcn_update_dpp(0, __float_as_int(v), 0x128, 0xF, 0xF, true)); // row_ror:8
  v += __int_as_float(__builtin_amdgcn_update_dpp(0, __float_as_int(v), 0x124, 0xF, 0xF, true)); // row_ror:4
  v += __int_as_float(__builtin_amdgcn_update_dpp(0, __float_as_int(v), 0x122, 0xF, 0xF, true)); // row_ror:2
  v += __int_as_float(__builtin_amdgcn_update_dpp(0, __float_as_int(v), 0x121, 0xF, 0xF, true)); // row_ror:1
  return v;
}

struct Buf { f32x4 kn0, kn1, q0, q1; float v, bx; };

__device__ __forceinline__ float core(const Buf& b, float db, f32x2 S2[4]) {
  const f32x2 k0 = {b.kn0.x, b.kn0.y}, k1 = {b.kn0.z, b.kn0.w};
  const f32x2 k2 = {b.kn1.x, b.kn1.y}, k3 = {b.kn1.z, b.kn1.w};
  f32x2 a0 = S2[0] * k0;
  f32x2 a1 = S2[1] * k1;
  a0 = __builtin_elementwise_fma(S2[2], k2, a0);
  a1 = __builtin_elementwise_fma(S2[3], k3, a1);
  const f32x2 ac = a0 + a1;
  const float r = sum16r(ac.x + ac.y);
  const float lg = fmaf(db, r, b.bx);              // bb pre-folded into bx
  const float beta = __builtin_amdgcn_rcpf(1.0f + __expf(-lg));
  const float cr = beta * (b.v - r);
  const f32x2 cr2 = {cr, cr};
  S2[0] = __builtin_elementwise_fma(cr2, k0, S2[0]);
  S2[1] = __builtin_elementwise_fma(cr2, k1, S2[1]);
  S2[2] = __builtin_elementwise_fma(cr2, k2, S2[2]);
  S2[3] = __builtin_elementwise_fma(cr2, k3, S2[3]);
  const f32x2 q0 = {b.q0.x, b.q0.y}, q1 = {b.q0.z, b.q0.w};
  const f32x2 q2 = {b.q1.x, b.q1.y}, q3 = {b.q1.z, b.q1.w};
  f32x2 o0 = S2[0] * q0;
  f32x2 o1 = S2[1] * q1;
  o0 = __builtin_elementwise_fma(S2[2], q2, o0);
  o1 = __builtin_elementwise_fma(S2[3], q3, o1);
  const f32x2 ao = o0 + o1;
  return sum16r(ao.x + ao.y);                      // raw od; silu deferred
}

__device__ __forceinline__ float fin(float od) {
  return od * od * __builtin_amdgcn_rcpf(1.0f + __expf(-od));
}

#define ADVB 131072u   // 4 slots * NB*PSTRIDE*4 bytes

__global__ __launch_bounds__(64)
__attribute__((amdgpu_waves_per_eu(1, 1)))
void scan_kernel(
    const float* __restrict__ proj, const float* __restrict__ S_in,
    const float* __restrict__ d_beta,
    float* __restrict__ out, float* __restrict__ S_out)
{
  const int lane = threadIdx.x & 63;
  const int batchA = blockIdx.x & 7;
  const int batchB = batchA + 8;
  const int grp = blockIdx.x >> 3;         // 0..31 row-group of 4
  const int cc = lane & 15;                // col chunk: 8 floats
  const int rloc = lane >> 4;              // 0..3
  const int row = grp * 4 + rloc;
  const bool w0 = (cc == 0);

  f32x2 S2A[4], S2B[4];
  {
    const f32x4* SpA = reinterpret_cast<const f32x4*>(
        S_in + ((size_t)batchA * ND + row) * ND + cc * 8);
    const f32x4 a0 = SpA[0], a1 = SpA[1];
    S2A[0] = (f32x2){a0.x, a0.y}; S2A[1] = (f32x2){a0.z, a0.w};
    S2A[2] = (f32x2){a1.x, a1.y}; S2A[3] = (f32x2){a1.z, a1.w};
    const f32x4* SpB = reinterpret_cast<const f32x4*>(
        S_in + ((size_t)batchB * ND + row) * ND + cc * 8);
    const f32x4 b0 = SpB[0], b1 = SpB[1];
    S2B[0] = (f32x2){b0.x, b0.y}; S2B[1] = (f32x2){b0.z, b0.w};
    S2B[2] = (f32x2){b1.x, b1.y}; S2B[3] = (f32x2){b1.z, b1.w};
  }
  const float db = d_beta[row];

  float* outpA = out + (size_t)batchA * ND + row;
  float* outpB = out + (size_t)batchB * ND + row;
  const size_t ostep = (size_t)NB * ND;

  // saddr-form byte offsets (u32, self-advancing). k at +0/+16; q at
  // +1024/+1040; v at +0; bx at +1024 (imm 13-bit ok).
  const unsigned kbA = (unsigned)(batchA * PSTRIDE + cc * 8) * 4u;
  const unsigned vbA = (unsigned)(batchA * PSTRIDE + 128 + row) * 4u;
  const unsigned kbB = (unsigned)(batchB * PSTRIDE + cc * 8) * 4u;
  const unsigned vbB = (unsigned)(batchB * PSTRIDE + 128 + row) * 4u;
  const unsigned sst = (unsigned)(NB * PSTRIDE) * 4u;
  unsigned kA0 = kbA + 0 * sst, kA1 = kbA + 1 * sst, kA2 = kbA + 2 * sst, kA3 = kbA + 3 * sst;
  unsigned vA0 = vbA + 0 * sst, vA1 = vbA + 1 * sst, vA2 = vbA + 2 * sst, vA3 = vbA + 3 * sst;
  unsigned kB0 = kbB + 0 * sst, kB1 = kbB + 1 * sst, kB2 = kbB + 2 * sst, kB3 = kbB + 3 * sst;
  unsigned vB0 = vbB + 0 * sst, vB1 = vbB + 1 * sst, vB2 = vbB + 2 * sst, vB3 = vbB + 3 * sst;

  Buf BA0, BA1, BA2, BA3, BB0, BB1, BB2, BB3;

#define LOADB(B, KO, VO)                                                       \
  do {                                                                         \
    asm volatile("global_load_dwordx4 %0, %1, %2"             : "=v"((B).kn0) : "v"(KO), "s"(proj)); \
    asm volatile("global_load_dwordx4 %0, %1, %2 offset:16"   : "=v"((B).kn1) : "v"(KO), "s"(proj)); \
    asm volatile("global_load_dwordx4 %0, %1, %2 offset:1024" : "=v"((B).q0)  : "v"(KO), "s"(proj)); \
    asm volatile("global_load_dwordx4 %0, %1, %2 offset:1040" : "=v"((B).q1)  : "v"(KO), "s"(proj)); \
    asm volatile("global_load_dword %0, %1, %2"               : "=v"((B).v)   : "v"(VO), "s"(proj)); \
    asm volatile("global_load_dword %0, %1, %2 offset:1024"   : "=v"((B).bx)  : "v"(VO), "s"(proj)); \
    KO += ADVB; VO += ADVB;                                                    \
  } while (0)

  LOADB(BA0, kA0, vA0); LOADB(BB0, kB0, vB0);
  LOADB(BA1, kA1, vA1); LOADB(BB1, kB1, vB1);
  LOADB(BA2, kA2, vA2); LOADB(BB2, kB2, vB2);
  LOADB(BA3, kA3, vA3); LOADB(BB3, kB3, vB3);

#define WAIT36 do { asm volatile("s_waitcnt vmcnt(36)" ::: "memory"); \
                    __builtin_amdgcn_sched_barrier(0); } while (0)

  float odA, odB;

#define SLOT(i)                                                           \
  do {                                                                    \
    { const float g = fin(odA); if (w0) *outpA = g; outpA += ostep; }     \
    { const float g = fin(odB); if (w0) *outpB = g; outpB += ostep; }     \
    WAIT36;                                                               \
    odA = core(BA##i, db, S2A);                                           \
    odB = core(BB##i, db, S2B);                                           \
    LOADB(BA##i, kA##i, vA##i);                                           \
    LOADB(BB##i, kB##i, vB##i);                                           \
    __builtin_amdgcn_sched_barrier(0);                                    \
  } while (0)

  // peel slot 0: no pending stores
  WAIT36;
  odA = core(BA0, db, S2A);
  odB = core(BB0, db, S2B);
  LOADB(BA0, kA0, vA0);
  LOADB(BB0, kB0, vB0);
  __builtin_amdgcn_sched_barrier(0);
  SLOT(1);
  SLOT(2);
  SLOT(3);

  // steady: consume steps 4..2043, reload 8..2047
  for (int t = 4; t < T_STEPS - 4; t += 4) {
    SLOT(0);
    SLOT(1);
    SLOT(2);
    SLOT(3);
  }

  // pending stores for step 2043
  { const float g = fin(odA); if (w0) *outpA = g; outpA += ostep; }
  { const float g = fin(odB); if (w0) *outpB = g; outpB += ostep; }
  asm volatile("s_waitcnt vmcnt(0)" ::: "memory");
  __builtin_amdgcn_sched_barrier(0);

#define TAIL(i)                                                           \
  do {                                                                    \
    odA = core(BA##i, db, S2A);                                           \
    { const float g = fin(odA); if (w0) *outpA = g; outpA += ostep; }     \
    odB = core(BB##i, db, S2B);                                           \
    { const float g = fin(odB); if (w0) *outpB = g; outpB += ostep; }     \
  } while (0)
  TAIL(0);
  TAIL(1);
  TAIL(2);
  TAIL(3);
#undef TAIL
#undef SLOT
#undef WAIT36
#undef LOADB

  {
    f32x4* SoA = reinterpret_cast<f32x4*>(
        S_out + ((size_t)batchA * ND + row) * ND + cc * 8);
    f32x4 s0, s1;
    s0.x = S2A[0].x; s0.y = S2A[0].y; s0.z = S2A[1].x; s0.w = S2A[1].y;
    s1.x = S2A[2].x; s1.y = S2A[2].y; s1.z = S2A[3].x; s1.w = S2A[3].y;
    SoA[0] = s0; SoA[1] = s1;
    f32x4* SoB = reinterpret_cast<f32x4*>(
        S_out + ((size_t)batchB * ND + row) * ND + cc * 8);
    f32x4 t0, t1;
    t0.x = S2B[0].x; t0.y = S2B[0].y; t0.z = S2B[1].x; t0.w = S2B[1].y;
    t1.x = S2B[2].x; t1.y = S2B[2].y; t1.z = S2B[3].x; t1.w = S2B[3].y;
    SoB[0] = t0; SoB[1] = t1;
  }
}

extern "C" void kernel_launch(void* const* d_in, const int* in_sizes, int n_in,
                              void* d_out, int out_size, void* d_ws, size_t ws_size,
                              hipStream_t stream) {
  const float* x  = (const float*)d_in[0];   // [2048][16][1024]
  const float* S0 = (const float*)d_in[1];   // [16][128][128]
  const float* Wk = (const float*)d_in[2];
  const float* Wv = (const float*)d_in[3];
  const float* Wq = (const float*)d_in[4];
  const float* Wb = (const float*)d_in[5];
  const float* db = (const float*)d_in[6];
  const float* bb = (const float*)d_in[7];
  float* out  = (float*)d_out;                           // [2048][16][128]
  float* Sout = out + (size_t)T_STEPS * NB * ND;         // [16][128][128]
  float* proj = (float*)d_ws;                            // [32768][512] = 64 MB

  dim3 ggrid(256, 4);
  proj_gemm<<<ggrid, 256, 0, stream>>>(x, Wk, Wv, Wq, Wb, proj);
  norm_k<<<8192, 256, 0, stream>>>(proj, bb);
  scan_kernel<<<256, 64, 0, stream>>>(proj, S0, db, out, Sout);
}

// Round 14
// 458.567 us; speedup vs baseline: 1.4339x; 1.4339x over previous
//
#include <hip/hip_runtime.h>
#include <hip/hip_bf16.h>

// E71 Delta cell: T=2048, B=16, D=1024, N=128
// proj layout in ws: [t][b][512] f32, cols 0..127=k_hat (after norm pass),
// 128..255=v, 256..383=q, 384..511=bx+bb (bb folded in norm pass)

#define T_STEPS 2048
#define NB 16
#define ND 128
#define KD 1024
#define PSTRIDE 512

typedef __attribute__((ext_vector_type(4))) float f32x4;
typedef __attribute__((ext_vector_type(2))) float f32x2;
typedef __attribute__((ext_vector_type(8))) short short8v;

__device__ __forceinline__ unsigned short f2bf(float f) {
  union { float f; unsigned int u; } c; c.f = f;
  unsigned int u = c.u;
  unsigned int r = u + 0x7fffu + ((u >> 16) & 1u);   // round-to-nearest-even
  return (unsigned short)(r >> 16);
}

// ---------------------------------------------------------------------------
// Projection GEMM (unchanged, ~56us): bf16 MFMA, 128x128 tile, BK=64,
// XOR-swizzled LDS.
// ---------------------------------------------------------------------------
__global__ __launch_bounds__(256) void proj_gemm(
    const float* __restrict__ X,
    const float* __restrict__ Wk, const float* __restrict__ Wv,
    const float* __restrict__ Wq, const float* __restrict__ Wb,
    float* __restrict__ C)
{
  __shared__ unsigned short As[128 * 64];
  __shared__ unsigned short Bs[128 * 64];
  const int tid = threadIdx.x;
  const int bm = blockIdx.x;
  const int bn = blockIdx.y;
  const float* W = (bn == 0) ? Wk : ((bn == 1) ? Wv : ((bn == 2) ? Wq : Wb));
  const int lane = tid & 63;
  const int wave = tid >> 6;
  const int wr = wave >> 1, wc = wave & 1;

  f32x4 acc[4][4];
#pragma unroll
  for (int i = 0; i < 4; i++)
#pragma unroll
    for (int j = 0; j < 4; j++) acc[i][j] = (f32x4){0.f, 0.f, 0.f, 0.f};

  for (int k0 = 0; k0 < KD; k0 += 64) {
    __syncthreads();
#pragma unroll
    for (int c = 0; c < 4; c++) {
      const int g = tid + c * 256;
      const int row = g >> 3;
      const int ch = g & 7;
      const int pos = ((ch ^ (row & 7)) * 8);
      {
        const float* ga = X + (size_t)(bm * 128 + row) * KD + k0 + ch * 8;
        float4 f0 = *(const float4*)(ga);
        float4 f1 = *(const float4*)(ga + 4);
        union { unsigned short u[8]; short8v v; } pk2;
        pk2.u[0] = f2bf(f0.x); pk2.u[1] = f2bf(f0.y);
        pk2.u[2] = f2bf(f0.z); pk2.u[3] = f2bf(f0.w);
        pk2.u[4] = f2bf(f1.x); pk2.u[5] = f2bf(f1.y);
        pk2.u[6] = f2bf(f1.z); pk2.u[7] = f2bf(f1.w);
        *reinterpret_cast<short8v*>(&As[row * 64 + pos]) = pk2.v;
      }
      {
        const float* gb = W + (size_t)row * KD + k0 + ch * 8;
        float4 f0 = *(const float4*)(gb);
        float4 f1 = *(const float4*)(gb + 4);
        union { unsigned short u[8]; short8v v; } pk2;
        pk2.u[0] = f2bf(f0.x); pk2.u[1] = f2bf(f0.y);
        pk2.u[2] = f2bf(f0.z); pk2.u[3] = f2bf(f0.w);
        pk2.u[4] = f2bf(f1.x); pk2.u[5] = f2bf(f1.y);
        pk2.u[6] = f2bf(f1.z); pk2.u[7] = f2bf(f1.w);
        *reinterpret_cast<short8v*>(&Bs[row * 64 + pos]) = pk2.v;
      }
    }
    __syncthreads();
#pragma unroll
    for (int kk = 0; kk < 2; kk++) {
      const int ch = kk * 4 + (lane >> 4);
      short8v a[4], b[4];
#pragma unroll
      for (int i = 0; i < 4; i++) {
        const int ar = wr * 64 + i * 16 + (lane & 15);
        a[i] = *reinterpret_cast<const short8v*>(&As[ar * 64 + ((ch ^ (ar & 7)) * 8)]);
        const int br = wc * 64 + i * 16 + (lane & 15);
        b[i] = *reinterpret_cast<const short8v*>(&Bs[br * 64 + ((ch ^ (br & 7)) * 8)]);
      }
#pragma unroll
      for (int i = 0; i < 4; i++)
#pragma unroll
        for (int j = 0; j < 4; j++)
          acc[i][j] = __builtin_amdgcn_mfma_f32_16x16x32_bf16(a[i], b[j], acc[i][j], 0, 0, 0);
    }
  }
#pragma unroll
  for (int i = 0; i < 4; i++)
#pragma unroll
    for (int j = 0; j < 4; j++)
#pragma unroll
      for (int r = 0; r < 4; r++) {
        const int row = bm * 128 + wr * 64 + i * 16 + (lane >> 4) * 4 + r;
        const int col = bn * 128 + wc * 64 + j * 16 + (lane & 15);
        C[(size_t)row * PSTRIDE + col] = acc[i][j][r];
      }
}

// ---------------------------------------------------------------------------
// k-normalization pre-pass: proj[row][0:128] <- k/(||k||+eps); also folds
// b_beta into the bx column: proj[row][384:512] += bb.
// ---------------------------------------------------------------------------
__global__ __launch_bounds__(256) void norm_k(float* __restrict__ proj,
                                              const float* __restrict__ b_beta) {
  const int lane = threadIdx.x & 63;
  const int wid = (blockIdx.x * 256 + threadIdx.x) >> 6;
  float* rowp = proj + (size_t)wid * PSTRIDE;
  float2 kv = *reinterpret_cast<float2*>(rowp + lane * 2);
  float ss = kv.x * kv.x + kv.y * kv.y;
  ss += __shfl_xor(ss, 1);
  ss += __shfl_xor(ss, 2);
  ss += __shfl_xor(ss, 4);
  ss += __shfl_xor(ss, 8);
  ss += __shfl_xor(ss, 16);
  ss += __shfl_xor(ss, 32);
  const float rn = 1.0f / (sqrtf(ss) + 1e-6f);
  kv.x *= rn; kv.y *= rn;
  *reinterpret_cast<float2*>(rowp + lane * 2) = kv;
  // fold bb into bx column
  float2 bx = *reinterpret_cast<float2*>(rowp + 384 + lane * 2);
  const float2 bb = *reinterpret_cast<const float2*>(b_beta + lane * 2);
  bx.x += bb.x; bx.y += bb.y;
  *reinterpret_cast<float2*>(rowp + 384 + lane * 2) = bx;
}

// ---------------------------------------------------------------------------
// Sequential scan, R14 = R12 geometry (1 row/wave, 2 waves/SIMD) + lean code.
// 2048 single-wave blocks; batch = bid&15 (all blocks of a batch on XCD
// batch%8 since bid%8 = batch%8); row = bid>>4. waves_per_eu(2,2): R12-proven
// no-spill at exactly our runtime occupancy (8 waves/CU).
// Cuts vs R12 (which ran ~2x fat): no chain-decoupling (TLP hides the chain
// at 2 waves/SIMD), canonical all-DPP wave64 reduce (row_shr 1/2/4/8 +
// row_bcast 15/31 -> lane63; v_readlane 63 -> SGPR broadcast; no shfl/DS),
// saddr-form loads with 2 self-advancing u32 offsets (no per-load 64-bit
// address math). Depth-8 asm ring, counted vmcnt(24): each slot drains
// exactly one store + one buf; slot t's buf is drained at slot t-1.
// Steady loop = 255 x 8 slots (reloads t+8 <= 2047, no OOB), then vmcnt(0)
// + 8 reload-free tail slots.
// ---------------------------------------------------------------------------
#define DPPADD(v, ctrl) \
  v += __int_as_float(__builtin_amdgcn_update_dpp(0, __float_as_int(v), ctrl, 0xF, 0xF, true))

__device__ __forceinline__ float sum64_l63(float v) {
  DPPADD(v, 0x111);  // row_shr:1
  DPPADD(v, 0x112);  // row_shr:2
  DPPADD(v, 0x114);  // row_shr:4
  DPPADD(v, 0x118);  // row_shr:8
  DPPADD(v, 0x142);  // row_bcast:15
  DPPADD(v, 0x143);  // row_bcast:31
  return v;          // lane63 holds the wave total
}

__device__ __forceinline__ float fin(float od) {
  return od * od * __builtin_amdgcn_rcpf(1.0f + __expf(-od));
}

#define SSTEPB 32768u   // NB*PSTRIDE*4 bytes per time step

__global__ __launch_bounds__(64)
__attribute__((amdgpu_waves_per_eu(2, 2)))
void scan_kernel(
    const float* __restrict__ proj, const float* __restrict__ S_in,
    const float* __restrict__ d_beta,
    float* __restrict__ out, float* __restrict__ S_out)
{
  const int lane = threadIdx.x & 63;
  const int batch = blockIdx.x & 15;
  const int row = blockIdx.x >> 4;     // 0..127

  f32x2 S2 = *reinterpret_cast<const f32x2*>(
      S_in + ((size_t)batch * ND + row) * ND + lane * 2);
  const float db = d_beta[row];

  // self-advancing u32 byte offsets (saddr form: base in SGPR pair)
  unsigned kO = (unsigned)((batch * PSTRIDE + lane * 2) * 4);       // k; q at +1024
  unsigned vO = (unsigned)((batch * PSTRIDE + 128 + row) * 4);      // v; bx at +1024
  float* outp = out + (size_t)batch * ND + row;
  const size_t ostep = (size_t)NB * ND;

  // flattened depth-8 ring
  f32x2 kn0, kn1, kn2, kn3, kn4, kn5, kn6, kn7;
  f32x2 q0, q1, q2, q3, q4, q5, q6, q7;
  float v0, v1, v2, v3, v4, v5, v6, v7;
  float x0, x1, x2, x3, x4, x5, x6, x7;

#define LOADB(i)                                                              \
  do {                                                                        \
    asm volatile("global_load_dwordx2 %0, %1, %2"             : "=v"(kn##i) : "v"(kO), "s"(proj)); \
    asm volatile("global_load_dwordx2 %0, %1, %2 offset:1024" : "=v"(q##i)  : "v"(kO), "s"(proj)); \
    asm volatile("global_load_dword %0, %1, %2"               : "=v"(v##i)  : "v"(vO), "s"(proj)); \
    asm volatile("global_load_dword %0, %1, %2 offset:1024"   : "=v"(x##i)  : "v"(vO), "s"(proj)); \
    kO += SSTEPB; vO += SSTEPB;                                               \
  } while (0)

  LOADB(0); LOADB(1); LOADB(2); LOADB(3);
  LOADB(4); LOADB(5); LOADB(6); LOADB(7);

#define WAIT24 do { asm volatile("s_waitcnt vmcnt(24)" ::: "memory"); \
                    __builtin_amdgcn_sched_barrier(0); } while (0)

#define CORE(i)                                                           \
  do {                                                                    \
    const f32x2 p = S2 * kn##i;                                           \
    const float rl = sum64_l63(p.x + p.y);                                \
    const float r = __int_as_float(                                       \
        __builtin_amdgcn_readlane(__float_as_int(rl), 63));               \
    const float lg = fmaf(db, r, x##i);          /* bb pre-folded */      \
    const float beta = __builtin_amdgcn_rcpf(1.0f + __expf(-lg));         \
    const float cr = beta * (v##i - r);                                   \
    const f32x2 cr2 = {cr, cr};                                           \
    S2 = __builtin_elementwise_fma(cr2, kn##i, S2);                       \
    const f32x2 ov = S2 * q##i;                                           \
    const float odl = sum64_l63(ov.x + ov.y);                             \
    if (lane == 63) *outp = fin(odl);                                     \
    outp += ostep;                                                        \
  } while (0)

#define SLOT(i) do { WAIT24; CORE(i); LOADB(i); } while (0)

  // steady: 255 x 8 slots consume t=0..2039, reload t=8..2047
  for (int it = 0; it < 255; ++it) {
    SLOT(0); SLOT(1); SLOT(2); SLOT(3);
    SLOT(4); SLOT(5); SLOT(6); SLOT(7);
  }
  // tail: consume t=2040..2047, no reloads
  asm volatile("s_waitcnt vmcnt(0)" ::: "memory");
  __builtin_amdgcn_sched_barrier(0);
  CORE(0); CORE(1); CORE(2); CORE(3);
  CORE(4); CORE(5); CORE(6); CORE(7);
#undef SLOT
#undef CORE
#undef WAIT24
#undef LOADB

  *reinterpret_cast<f32x2*>(
      S_out + ((size_t)batch * ND + row) * ND + lane * 2) = S2;
}

extern "C" void kernel_launch(void* const* d_in, const int* in_sizes, int n_in,
                              void* d_out, int out_size, void* d_ws, size_t ws_size,
                              hipStream_t stream) {
  const float* x  = (const float*)d_in[0];   // [2048][16][1024]
  const float* S0 = (const float*)d_in[1];   // [16][128][128]
  const float* Wk = (const float*)d_in[2];
  const float* Wv = (const float*)d_in[3];
  const float* Wq = (const float*)d_in[4];
  const float* Wb = (const float*)d_in[5];
  const float* db = (const float*)d_in[6];
  const float* bb = (const float*)d_in[7];
  float* out  = (float*)d_out;                           // [2048][16][128]
  float* Sout = out + (size_t)T_STEPS * NB * ND;         // [16][128][128]
  float* proj = (float*)d_ws;                            // [32768][512] = 64 MB

  dim3 ggrid(256, 4);
  proj_gemm<<<ggrid, 256, 0, stream>>>(x, Wk, Wv, Wq, Wb, proj);
  norm_k<<<8192, 256, 0, stream>>>(proj, bb);
  scan_kernel<<<2048, 64, 0, stream>>>(proj, S0, db, out, Sout);
}